// Round 6
// baseline (230.617 us; speedup 1.0000x reference)
//
#include <hip/hip_runtime.h>
#include <hip/hip_bf16.h>
#include <stdint.h>

// Problem constants
#define Bc 4
#define Tc 2048
#define Dc 512
#define Hc 8
// DH = 64, 3D = 1536, M = B*T = 8192

typedef __bf16 bf16x8 __attribute__((ext_vector_type(8)));
typedef float  f32x4  __attribute__((ext_vector_type(4)));
typedef float  f32x16 __attribute__((ext_vector_type(16)));
typedef unsigned short u16x8 __attribute__((ext_vector_type(8)));

__device__ __forceinline__ unsigned short f2b(float f) {
  union { float f; unsigned u; } v; v.f = f;
  unsigned r = v.u + 0x7fffu + ((v.u >> 16) & 1u);   // RNE f32->bf16
  return (unsigned short)(r >> 16);
}

__device__ __forceinline__ bf16x8 ld_frag(const unsigned short* p) {
  u16x8 u = *(const u16x8*)p;
  return __builtin_bit_cast(bf16x8, u);
}

__device__ __forceinline__ void gload_lds16(const unsigned short* g, unsigned short* l) {
  __builtin_amdgcn_global_load_lds((const __attribute__((address_space(1))) void*)g,
                                   (__attribute__((address_space(3))) void*)l,
                                   16, 0, 0);
}

__device__ __forceinline__ unsigned cvtpk_bf16(float lo, float hi) {
  unsigned r;
  asm("v_cvt_pk_bf16_f32 %0, %1, %2" : "=v"(r) : "v"(lo), "v"(hi));
  return r;
}

// exchanges upper half of a with lower half of b (v_permlane32_swap_b32 a, b)
__device__ __forceinline__ void perm32swap(unsigned& a, unsigned& b) {
  asm volatile("v_permlane32_swap_b32 %0, %1" : "+v"(a), "+v"(b));
}

// ---------------- f32 -> bf16 convert (vectorized) ----------------
__global__ __launch_bounds__(256) void cvt_bf16(const float* __restrict__ in,
                                                unsigned short* __restrict__ out, int n) {
  int i = (blockIdx.x * 256 + threadIdx.x) * 8;
  if (i >= n) return;
  float4 a = *(const float4*)&in[i];
  float4 b = *(const float4*)&in[i + 4];
  u16x8 r;
  r[0] = f2b(a.x); r[1] = f2b(a.y); r[2] = f2b(a.z); r[3] = f2b(a.w);
  r[4] = f2b(b.x); r[5] = f2b(b.y); r[6] = f2b(b.z); r[7] = f2b(b.w);
  *(u16x8*)&out[i] = r;
}

// ---------------- f32 [R][C] -> bf16 [C][R] tiled transpose ----------------
__global__ __launch_bounds__(256) void transp_bf16(const float* __restrict__ in,
                                                   unsigned short* __restrict__ out,
                                                   int R, int C) {
  __shared__ float tile[32][33];
  int c0 = blockIdx.x * 32, r0 = blockIdx.y * 32;
  int lx = threadIdx.x & 31, ly = threadIdx.x >> 5;   // 32 x 8
  #pragma unroll
  for (int i = 0; i < 32; i += 8) tile[ly + i][lx] = in[(size_t)(r0 + ly + i) * C + c0 + lx];
  __syncthreads();
  #pragma unroll
  for (int i = 0; i < 32; i += 8) out[(size_t)(c0 + ly + i) * R + r0 + lx] = f2b(tile[lx][ly + i]);
}

// ---------------- bf16 V pre-transpose: qkv V-part -> vtg[(b*512+dg)][T] ----------------
__global__ __launch_bounds__(256) void transp_v(const unsigned short* __restrict__ qkv,
                                                unsigned short* __restrict__ vtg) {
  __shared__ unsigned short tile[32][34];
  int t0 = blockIdx.x * 32;          // 64
  int d0 = blockIdx.y * 32;          // 16
  int b  = blockIdx.z;               // 4
  int lx = threadIdx.x & 31, ly = threadIdx.x >> 5;   // 32 x 8
  #pragma unroll
  for (int i = 0; i < 32; i += 8)
    tile[ly + i][lx] = qkv[(size_t)(b * Tc + t0 + ly + i) * 1536 + 1024 + d0 + lx];
  __syncthreads();
  #pragma unroll
  for (int i = 0; i < 32; i += 8)
    vtg[(size_t)(b * 512 + d0 + ly + i) * Tc + t0 + lx] = tile[lx][ly + i];
}

// ---------------- bf16 GEMM: C[M,N] = A[M,K] * Bt[N,K]^T ----------------
template <int N, int OUTF32>
__global__ __launch_bounds__(256) void gemm_bt(const unsigned short* __restrict__ A,
                                               const unsigned short* __restrict__ Bt,
                                               void* __restrict__ Cout, int M, int K) {
  __shared__ unsigned short As[128 * 32];
  __shared__ unsigned short Bs[128 * 32];
  const int tid = threadIdx.x;
  const int lane = tid & 63;
  const int wid = tid >> 6;
  const int wm = (wid >> 1) * 64;
  const int wn = (wid & 1) * 64;
  const int m0 = blockIdx.x * 128;
  const int n0 = blockIdx.y * 128;
  const int l15 = lane & 15;
  const int lg = lane >> 4;

  f32x4 acc[4][4];
  #pragma unroll
  for (int i = 0; i < 4; i++)
    #pragma unroll
    for (int j = 0; j < 4; j++) acc[i][j] = (f32x4){0.f, 0.f, 0.f, 0.f};

  const int srow = tid >> 2;
  const int scol = (tid & 3) * 8;

  for (int k0 = 0; k0 < K; k0 += 32) {
    __syncthreads();
    gload_lds16(&A[(size_t)(m0 + srow) * K + k0 + scol],      &As[tid * 8]);
    gload_lds16(&A[(size_t)(m0 + 64 + srow) * K + k0 + scol], &As[2048 + tid * 8]);
    gload_lds16(&Bt[(size_t)(n0 + srow) * K + k0 + scol],      &Bs[tid * 8]);
    gload_lds16(&Bt[(size_t)(n0 + 64 + srow) * K + k0 + scol], &Bs[2048 + tid * 8]);
    __syncthreads();
    bf16x8 af[4], bfr[4];
    #pragma unroll
    for (int m = 0; m < 4; m++) af[m] = ld_frag(&As[(wm + m * 16 + l15) * 32 + lg * 8]);
    #pragma unroll
    for (int n = 0; n < 4; n++) bfr[n] = ld_frag(&Bs[(wn + n * 16 + l15) * 32 + lg * 8]);
    #pragma unroll
    for (int m = 0; m < 4; m++)
      #pragma unroll
      for (int n = 0; n < 4; n++)
        acc[m][n] = __builtin_amdgcn_mfma_f32_16x16x32_bf16(af[m], bfr[n], acc[m][n], 0, 0, 0);
  }

  #pragma unroll
  for (int m = 0; m < 4; m++)
    #pragma unroll
    for (int n = 0; n < 4; n++)
      #pragma unroll
      for (int j = 0; j < 4; j++) {
        int row = m0 + wm + m * 16 + lg * 4 + j;
        int col = n0 + wn + n * 16 + l15;
        float v = acc[m][n][j];
        if (OUTF32) ((float*)Cout)[(size_t)row * N + col] = v;
        else ((unsigned short*)Cout)[(size_t)row * N + col] = f2b(v);
      }
}

// ---------------- fused attention (32x32 MFMA, in-register P, static dbuf) ----------------
// Block: 4 waves x 32 q-rows (QBLK=128) per (b,h); grid 512 = 2 blocks/CU.
// KBLK=64 double-buffered (static names KsA/KsB/VsA/VsB -> no alias stalls),
// ONE barrier per k-tile; stage(next) issued before compute(cur).
// Swapped QK^T (mfma32(K,Q)): lane holds S^T[16 keys][q=lane&31]; P stays in
// registers via v_cvt_pk_bf16_f32 + v_permlane32_swap_b32 -> PV A-fragments.
// K/V LDS chunk swizzle c ^= (row>>2)&7: 32-row b128 frag reads are 2-way (free).
__global__ __launch_bounds__(256) void attn_kernel(const unsigned short* __restrict__ qkv,
                                                   const unsigned short* __restrict__ vtg,
                                                   const float* __restrict__ bias,
                                                   const int* __restrict__ amask,
                                                   unsigned short* __restrict__ ctx) {
  __shared__ unsigned short KsA[64 * 64];
  __shared__ unsigned short VsA[64 * 64];
  __shared__ unsigned short KsB[64 * 64];
  __shared__ unsigned short VsB[64 * 64];

  const int NQ = Tc / 128;                // 16 q-tiles
  const int bid = blockIdx.x;
  const int b = bid / (Hc * NQ);
  const int h = (bid / NQ) % Hc;
  const int q0 = (bid % NQ) * 128;
  const int tid = threadIdx.x;
  const int lane = tid & 63;
  const int w = tid >> 6;
  const int l31 = lane & 31;
  const int hi = lane >> 5;
  const int swz = l31 >> 2;               // 0..7 XOR swizzle key

  const float LOG2E = 1.44269504f;
  const float SC = 0.125f * LOG2E;

  // Q fragments (B operand): q = q0 + w*32 + l31, k-chunk kc: d = kc*16 + hi*8
  const int qrow = q0 + w * 32 + l31;
  const size_t qoff = (size_t)(b * Tc + qrow) * 1536 + h * 64;
  bf16x8 qf0 = ld_frag(&qkv[qoff + 0 * 16 + hi * 8]);
  bf16x8 qf1 = ld_frag(&qkv[qoff + 1 * 16 + hi * 8]);
  bf16x8 qf2 = ld_frag(&qkv[qoff + 2 * 16 + hi * 8]);
  bf16x8 qf3 = ld_frag(&qkv[qoff + 3 * 16 + hi * 8]);

  u16x8 ou;
  #pragma unroll
  for (int e = 0; e < 8; e++) ou[e] = 0x3f80;   // bf16 1.0
  const bf16x8 ones = __builtin_bit_cast(bf16x8, ou);

  f32x16 o0, o1, osum;
  #pragma unroll
  for (int i = 0; i < 16; i++) { o0[i] = 0.f; o1[i] = 0.f; osum[i] = 0.f; }

  // staging geometry
  const size_t kcol = (size_t)(b * Tc) * 1536 + 512 + h * 64;
  const unsigned short* vrow = &vtg[(size_t)(b * 512 + h * 64) * Tc];
  const int sr = tid >> 3;               // 0..31
  const int sc_ = tid & 7;
  const int sgc = sc_ ^ ((sr >> 2) & 7); // source chunk (same for row sr and sr+32)

  auto stage = [&](unsigned short* ks, unsigned short* vs, int kt) {
    const size_t kbase = kcol + (size_t)kt * 1536;
    gload_lds16(&qkv[kbase + (size_t)sr * 1536 + sgc * 8],        &ks[tid * 8]);
    gload_lds16(&qkv[kbase + (size_t)(sr + 32) * 1536 + sgc * 8], &ks[2048 + tid * 8]);
    gload_lds16(&vrow[(size_t)sr * Tc + kt + sgc * 8],            &vs[tid * 8]);
    gload_lds16(&vrow[(size_t)(sr + 32) * Tc + kt + sgc * 8],     &vs[2048 + tid * 8]);
  };

  // bias: ONE row per lane (q = qrow); keys per reg r: kt2*32 + (r>>2)*8 + hi*4 + (r&3)
  const float* bq = bias + (size_t)(b * Tc + qrow) * Tc;
  const int* mq = amask + b * Tc;

  auto loadBias = [&](int kt, float4* bb) {
    #pragma unroll
    for (int kt2 = 0; kt2 < 2; kt2++)
      #pragma unroll
      for (int g = 0; g < 4; g++) {
        const int idx = kt + kt2 * 32 + g * 8 + hi * 4;
        float4 bv = *(const float4*)&bq[idx];
        int4 mm = *(const int4*)&mq[idx];
        float4 r;
        r.x = mm.x ? bv.x * LOG2E : -1e30f;
        r.y = mm.y ? bv.y * LOG2E : -1e30f;
        r.z = mm.z ? bv.z * LOG2E : -1e30f;
        r.w = mm.w ? bv.w * LOG2E : -1e30f;
        bb[kt2 * 4 + g] = r;
      }
  };

  auto compute = [&](const unsigned short* ks, const unsigned short* vs,
                     const float4* bc, int ktn, float4* bn) {
    #pragma unroll
    for (int kt2 = 0; kt2 < 2; kt2++) {
      // ---- QK^T: S^T[key][q], keys kt2*32.., DH=64 as 4 k16-chunks ----
      f32x16 s;
      #pragma unroll
      for (int i = 0; i < 16; i++) s[i] = 0.f;
      bf16x8 ka0 = ld_frag(&ks[(kt2 * 32 + l31) * 64 + ((0 + hi) ^ swz) * 8]);
      bf16x8 ka1 = ld_frag(&ks[(kt2 * 32 + l31) * 64 + ((2 + hi) ^ swz) * 8]);
      bf16x8 ka2 = ld_frag(&ks[(kt2 * 32 + l31) * 64 + ((4 + hi) ^ swz) * 8]);
      bf16x8 ka3 = ld_frag(&ks[(kt2 * 32 + l31) * 64 + ((6 + hi) ^ swz) * 8]);
      __builtin_amdgcn_s_setprio(1);
      s = __builtin_amdgcn_mfma_f32_32x32x16_bf16(ka0, qf0, s, 0, 0, 0);
      s = __builtin_amdgcn_mfma_f32_32x32x16_bf16(ka1, qf1, s, 0, 0, 0);
      s = __builtin_amdgcn_mfma_f32_32x32x16_bf16(ka2, qf2, s, 0, 0, 0);
      s = __builtin_amdgcn_mfma_f32_32x32x16_bf16(ka3, qf3, s, 0, 0, 0);
      __builtin_amdgcn_s_setprio(0);

      // overlap: prefetch next tile's bias during first half's softmax window
      if (kt2 == 0 && ktn < Tc) loadBias(ktn, bn);

      // ---- p = exp2(s*SC + bias*log2e + mask) ----
      float p[16];
      #pragma unroll
      for (int r = 0; r < 16; r++) {
        const float bb = ((const float*)&bc[kt2 * 4 + (r >> 2)])[r & 3];
        p[r] = exp2f(fmaf(s[r], SC, bb));
      }

      // ---- pack to PV A-frags: 8 cvt_pk + 4 permlane32_swap ----
      unsigned pk0 = cvtpk_bf16(p[0], p[1]);
      unsigned pk1 = cvtpk_bf16(p[2], p[3]);
      unsigned pk2 = cvtpk_bf16(p[4], p[5]);
      unsigned pk3 = cvtpk_bf16(p[6], p[7]);
      unsigned pk4 = cvtpk_bf16(p[8], p[9]);
      unsigned pk5 = cvtpk_bf16(p[10], p[11]);
      unsigned pk6 = cvtpk_bf16(p[12], p[13]);
      unsigned pk7 = cvtpk_bf16(p[14], p[15]);
      perm32swap(pk0, pk2);   // -> w0, w2 of keys 0-15
      perm32swap(pk1, pk3);   // -> w1, w3
      perm32swap(pk4, pk6);   // -> w0, w2 of keys 16-31
      perm32swap(pk5, pk7);   // -> w1, w3
      uint4 pa0u = {pk0, pk1, pk2, pk3};
      uint4 pa1u = {pk4, pk5, pk6, pk7};
      bf16x8 pa0 = __builtin_bit_cast(bf16x8, pa0u);
      bf16x8 pa1 = __builtin_bit_cast(bf16x8, pa1u);

      // ---- PV + row-sum (A rows = q, B cols = d) ----
      bf16x8 vb00 = ld_frag(&vs[(0 * 32 + l31) * 64 + (((kt2 * 2 + 0) * 2 + hi) ^ swz) * 8]);
      bf16x8 vb01 = ld_frag(&vs[(1 * 32 + l31) * 64 + (((kt2 * 2 + 0) * 2 + hi) ^ swz) * 8]);
      bf16x8 vb10 = ld_frag(&vs[(0 * 32 + l31) * 64 + (((kt2 * 2 + 1) * 2 + hi) ^ swz) * 8]);
      bf16x8 vb11 = ld_frag(&vs[(1 * 32 + l31) * 64 + (((kt2 * 2 + 1) * 2 + hi) ^ swz) * 8]);
      __builtin_amdgcn_s_setprio(1);
      osum = __builtin_amdgcn_mfma_f32_32x32x16_bf16(pa0, ones, osum, 0, 0, 0);
      osum = __builtin_amdgcn_mfma_f32_32x32x16_bf16(pa1, ones, osum, 0, 0, 0);
      o0 = __builtin_amdgcn_mfma_f32_32x32x16_bf16(pa0, vb00, o0, 0, 0, 0);
      o1 = __builtin_amdgcn_mfma_f32_32x32x16_bf16(pa0, vb01, o1, 0, 0, 0);
      o0 = __builtin_amdgcn_mfma_f32_32x32x16_bf16(pa1, vb10, o0, 0, 0, 0);
      o1 = __builtin_amdgcn_mfma_f32_32x32x16_bf16(pa1, vb11, o1, 0, 0, 0);
      __builtin_amdgcn_s_setprio(0);
    }
  };

  float4 bufC[8], bufN[8];
  stage(KsA, VsA, 0);
  loadBias(0, bufC);

  for (int kt = 0; kt < Tc; kt += 128) {
    __syncthreads();                       // drains stage(A, kt)
    stage(KsB, VsB, kt + 64);              // in flight during compute(A)
    __builtin_amdgcn_sched_barrier(0);
    compute(KsA, VsA, bufC, kt + 64, bufN);
    __syncthreads();                       // drains stage(B, kt+64)
    if (kt + 128 < Tc) stage(KsA, VsA, kt + 128);
    __builtin_amdgcn_sched_barrier(0);
    compute(KsB, VsB, bufN, kt + 128, bufC);
  }

  // epilogue: o rows q = (r&3)+8*(r>>2)+4*hi; cols d = l31 (+32 for o1)
  #pragma unroll
  for (int r = 0; r < 16; r++) {
    const int qr = q0 + w * 32 + (r & 3) + 8 * (r >> 2) + 4 * hi;
    const float inv = 1.0f / osum[r];
    const size_t base = (size_t)(b * Tc + qr) * Dc + h * 64;
    ctx[base + l31]      = f2b(o0[r] * inv);
    ctx[base + 32 + l31] = f2b(o1[r] * inv);
  }
}

// ---------------- launcher ----------------
extern "C" void kernel_launch(void* const* d_in, const int* in_sizes, int n_in,
                              void* d_out, int out_size, void* d_ws, size_t ws_size,
                              hipStream_t stream) {
  const float* x     = (const float*)d_in[0];
  const int*   amask = (const int*)d_in[1];
  const float* bias  = (const float*)d_in[2];
  const float* Wqkv  = (const float*)d_in[3];
  const float* Wout  = (const float*)d_in[4];
  float* out = (float*)d_out;
  char* ws = (char*)d_ws;

  // ws layout (bytes): xb 8,388,608 | wqkvT 1,572,864 | woutT 524,288 |
  //   qkv 25,165,824 | ctx 8,388,608 | vtg 8,388,608   (total ~52.4 MB)
  unsigned short* xb    = (unsigned short*)(ws + 0);
  unsigned short* wqkvT = (unsigned short*)(ws + 8388608);
  unsigned short* woutT = (unsigned short*)(ws + 9961472);
  unsigned short* qkv   = (unsigned short*)(ws + 10485760);
  unsigned short* ctx   = (unsigned short*)(ws + 35651584);
  unsigned short* vtg   = (unsigned short*)(ws + 44040192);

  cvt_bf16<<<2048, 256, 0, stream>>>(x, xb, Bc * Tc * Dc);
  transp_bf16<<<dim3(48, 16), 256, 0, stream>>>(Wqkv, wqkvT, 512, 1536);
  transp_bf16<<<dim3(16, 16), 256, 0, stream>>>(Wout, woutT, 512, 512);
  gemm_bt<1536, 0><<<dim3(64, 12), 256, 0, stream>>>(xb, wqkvT, (void*)qkv, 8192, 512);
  transp_v<<<dim3(64, 16, 4), 256, 0, stream>>>(qkv, vtg);
  attn_kernel<<<512, 256, 0, stream>>>(qkv, vtg, bias, amask, ctx);
  gemm_bt<512, 1><<<dim3(64, 4), 256, 0, stream>>>(ctx, woutT, (void*)out, 8192, 512);
}

// Round 7
// 167.376 us; speedup vs baseline: 1.3778x; 1.3778x over previous
//
#include <hip/hip_runtime.h>
#include <hip/hip_bf16.h>
#include <stdint.h>

// Problem constants
#define Bc 4
#define Tc 2048
#define Dc 512
#define Hc 8
// DH = 64, 3D = 1536, M = B*T = 8192

typedef __bf16 bf16x8 __attribute__((ext_vector_type(8)));
typedef float  f32x4  __attribute__((ext_vector_type(4)));
typedef unsigned short u16x8 __attribute__((ext_vector_type(8)));

__device__ __forceinline__ unsigned short f2b(float f) {
  union { float f; unsigned u; } v; v.f = f;
  unsigned r = v.u + 0x7fffu + ((v.u >> 16) & 1u);   // RNE f32->bf16
  return (unsigned short)(r >> 16);
}

__device__ __forceinline__ bf16x8 ld_frag(const unsigned short* p) {
  u16x8 u = *(const u16x8*)p;
  return __builtin_bit_cast(bf16x8, u);
}

__device__ __forceinline__ void gload_lds16(const unsigned short* g, unsigned short* l) {
  __builtin_amdgcn_global_load_lds((const __attribute__((address_space(1))) void*)g,
                                   (__attribute__((address_space(3))) void*)l,
                                   16, 0, 0);
}

__device__ __forceinline__ unsigned cvtpk_bf16(float lo, float hi) {
  unsigned r;
  asm("v_cvt_pk_bf16_f32 %0, %1, %2" : "=v"(r) : "v"(lo), "v"(hi));
  return r;
}

// ---------------- f32 -> bf16 convert (vectorized) ----------------
__global__ __launch_bounds__(256) void cvt_bf16(const float* __restrict__ in,
                                                unsigned short* __restrict__ out, int n) {
  int i = (blockIdx.x * 256 + threadIdx.x) * 8;
  if (i >= n) return;
  float4 a = *(const float4*)&in[i];
  float4 b = *(const float4*)&in[i + 4];
  u16x8 r;
  r[0] = f2b(a.x); r[1] = f2b(a.y); r[2] = f2b(a.z); r[3] = f2b(a.w);
  r[4] = f2b(b.x); r[5] = f2b(b.y); r[6] = f2b(b.z); r[7] = f2b(b.w);
  *(u16x8*)&out[i] = r;
}

// ---------------- f32 [R][C] -> bf16 [C][R] tiled transpose ----------------
__global__ __launch_bounds__(256) void transp_bf16(const float* __restrict__ in,
                                                   unsigned short* __restrict__ out,
                                                   int R, int C) {
  __shared__ float tile[32][33];
  int c0 = blockIdx.x * 32, r0 = blockIdx.y * 32;
  int lx = threadIdx.x & 31, ly = threadIdx.x >> 5;   // 32 x 8
  #pragma unroll
  for (int i = 0; i < 32; i += 8) tile[ly + i][lx] = in[(size_t)(r0 + ly + i) * C + c0 + lx];
  __syncthreads();
  #pragma unroll
  for (int i = 0; i < 32; i += 8) out[(size_t)(c0 + ly + i) * R + r0 + lx] = f2b(tile[lx][ly + i]);
}

// ---------------- bf16 V pre-transpose: qkv V-part -> vtg[(b*512+dg)][T] ----------------
__global__ __launch_bounds__(256) void transp_v(const unsigned short* __restrict__ qkv,
                                                unsigned short* __restrict__ vtg) {
  __shared__ unsigned short tile[32][34];
  int t0 = blockIdx.x * 32;          // 64
  int d0 = blockIdx.y * 32;          // 16
  int b  = blockIdx.z;               // 4
  int lx = threadIdx.x & 31, ly = threadIdx.x >> 5;   // 32 x 8
  #pragma unroll
  for (int i = 0; i < 32; i += 8)
    tile[ly + i][lx] = qkv[(size_t)(b * Tc + t0 + ly + i) * 1536 + 1024 + d0 + lx];
  __syncthreads();
  #pragma unroll
  for (int i = 0; i < 32; i += 8)
    vtg[(size_t)(b * 512 + d0 + ly + i) * Tc + t0 + lx] = tile[lx][ly + i];
}

// ---------------- bf16 GEMM: C[M,N] = A[M,K] * Bt[N,K]^T ----------------
template <int N, int OUTF32>
__global__ __launch_bounds__(256) void gemm_bt(const unsigned short* __restrict__ A,
                                               const unsigned short* __restrict__ Bt,
                                               void* __restrict__ Cout, int M, int K) {
  __shared__ unsigned short As[128 * 32];
  __shared__ unsigned short Bs[128 * 32];
  const int tid = threadIdx.x;
  const int lane = tid & 63;
  const int wid = tid >> 6;
  const int wm = (wid >> 1) * 64;
  const int wn = (wid & 1) * 64;
  const int m0 = blockIdx.x * 128;
  const int n0 = blockIdx.y * 128;
  const int l15 = lane & 15;
  const int lg = lane >> 4;

  f32x4 acc[4][4];
  #pragma unroll
  for (int i = 0; i < 4; i++)
    #pragma unroll
    for (int j = 0; j < 4; j++) acc[i][j] = (f32x4){0.f, 0.f, 0.f, 0.f};

  const int srow = tid >> 2;
  const int scol = (tid & 3) * 8;

  for (int k0 = 0; k0 < K; k0 += 32) {
    __syncthreads();
    gload_lds16(&A[(size_t)(m0 + srow) * K + k0 + scol],      &As[tid * 8]);
    gload_lds16(&A[(size_t)(m0 + 64 + srow) * K + k0 + scol], &As[2048 + tid * 8]);
    gload_lds16(&Bt[(size_t)(n0 + srow) * K + k0 + scol],      &Bs[tid * 8]);
    gload_lds16(&Bt[(size_t)(n0 + 64 + srow) * K + k0 + scol], &Bs[2048 + tid * 8]);
    __syncthreads();
    bf16x8 af[4], bfr[4];
    #pragma unroll
    for (int m = 0; m < 4; m++) af[m] = ld_frag(&As[(wm + m * 16 + l15) * 32 + lg * 8]);
    #pragma unroll
    for (int n = 0; n < 4; n++) bfr[n] = ld_frag(&Bs[(wn + n * 16 + l15) * 32 + lg * 8]);
    #pragma unroll
    for (int m = 0; m < 4; m++)
      #pragma unroll
      for (int n = 0; n < 4; n++)
        acc[m][n] = __builtin_amdgcn_mfma_f32_16x16x32_bf16(af[m], bfr[n], acc[m][n], 0, 0, 0);
  }

  #pragma unroll
  for (int m = 0; m < 4; m++)
    #pragma unroll
    for (int n = 0; n < 4; n++)
      #pragma unroll
      for (int j = 0; j < 4; j++) {
        int row = m0 + wm + m * 16 + lg * 4 + j;
        int col = n0 + wn + n * 16 + l15;
        float v = acc[m][n][j];
        if (OUTF32) ((float*)Cout)[(size_t)row * N + col] = v;
        else ((unsigned short*)Cout)[(size_t)row * N + col] = f2b(v);
      }
}

// ---------------- fused attention (swapped QK^T, XOR P-tile, no-max softmax) ----------------
// Round-2 champion structure (2 barriers/tile, single buffer) + verified upgrades:
// swapped QK^T (s = mfma(K,Q): per-lane S at q=l15, keys t2*16+lg*4+j) enabling
// float4 bias + int4 mask loads; P packed via v_cvt_pk_bf16_f32 and stored with
// the round-2-proven chunk-XOR layout (stride 64, c' = c ^ (q&7)) -> b64 writes
// ~free, pa b128 reads 8/bank even (0 conflicts). setprio(1) around MFMA clusters.
__global__ __launch_bounds__(256) void attn_kernel(const unsigned short* __restrict__ qkv,
                                                   const unsigned short* __restrict__ vtg,
                                                   const float* __restrict__ bias,
                                                   const int* __restrict__ amask,
                                                   unsigned short* __restrict__ ctx) {
  __shared__ unsigned short Ks[64 * 64];
  __shared__ unsigned short Vs[64 * 64];     // Vs[d][key], chunk-swizzled
  __shared__ unsigned short Pt[4][16 * 64];  // per-wave P[q][key], chunk-XOR c^(q&7)

  const int NQ = Tc / 64;                 // 32 q-tiles
  const int bid = blockIdx.x;
  const int b = bid / (Hc * NQ);
  const int h = (bid / NQ) % Hc;
  const int q0 = (bid % NQ) * 64;
  const int tid = threadIdx.x;
  const int lane = tid & 63;
  const int w = tid >> 6;
  const int l15 = lane & 15;
  const int lg = lane >> 4;

  const float LOG2E = 1.44269504f;
  const float SC = 0.125f * LOG2E;

  // Q fragments (B operand; lane l15 holds q-row q0+w*16+l15)
  const int qrow = q0 + w * 16 + l15;
  const size_t qoff = (size_t)(b * Tc + qrow) * 1536 + h * 64;
  bf16x8 qf0 = ld_frag(&qkv[qoff + lg * 8]);
  bf16x8 qf1 = ld_frag(&qkv[qoff + 32 + lg * 8]);

  // ones fragment for row-sum MFMA
  u16x8 ou;
  #pragma unroll
  for (int e = 0; e < 8; e++) ou[e] = 0x3f80;   // bf16 1.0
  const bf16x8 ones = __builtin_bit_cast(bf16x8, ou);

  f32x4 o[4];
  f32x4 osum = (f32x4){0.f, 0.f, 0.f, 0.f};
  #pragma unroll
  for (int n = 0; n < 4; n++) o[n] = (f32x4){0.f, 0.f, 0.f, 0.f};

  const int skey = tid >> 3;            // 0..31 (K key-row / V d-row)
  const int sc = tid & 7;               // chunk slot
  const int sgc = sc ^ (skey & 7);      // pre-swizzled source chunk

  const size_t kcol = (size_t)b * Tc * 1536 + 512 + h * 64;
  const unsigned short* vrow = &vtg[(size_t)(b * 512 + h * 64) * Tc];

  // bias row is lane-fixed (q = q0 + w*16 + l15); keys advance along the row
  const float* bq = bias + (size_t)(b * Tc + q0 + w * 16 + l15) * Tc;
  const int* mq = amask + b * Tc;

  unsigned short* ptw = &Pt[w][0];

  for (int kt = 0; kt < Tc; kt += 64) {
    __syncthreads();
    // ---- stage K tile (64 keys x 64 d) and V tile (64 d x 64 keys) ----
    {
      const size_t kbase = kcol + (size_t)kt * 1536;
      gload_lds16(&qkv[kbase + (size_t)skey * 1536 + sgc * 8],        &Ks[tid * 8]);
      gload_lds16(&qkv[kbase + (size_t)(skey + 32) * 1536 + sgc * 8], &Ks[2048 + tid * 8]);
      gload_lds16(&vrow[(size_t)skey * Tc + kt + sgc * 8],        &Vs[tid * 8]);
      gload_lds16(&vrow[(size_t)(skey + 32) * Tc + kt + sgc * 8], &Vs[2048 + tid * 8]);
    }
    // ---- prefetch bias (float4) + mask (int4), fold mask, pre-mul log2e ----
    float bf_[4][4];
    #pragma unroll
    for (int t2 = 0; t2 < 4; t2++) {
      float4 bb = *(const float4*)&bq[kt + t2 * 16 + lg * 4];
      int4 mm = *(const int4*)&mq[kt + t2 * 16 + lg * 4];
      bf_[t2][0] = mm.x ? bb.x * LOG2E : -1e30f;
      bf_[t2][1] = mm.y ? bb.y * LOG2E : -1e30f;
      bf_[t2][2] = mm.z ? bb.z * LOG2E : -1e30f;
      bf_[t2][3] = mm.w ? bb.w * LOG2E : -1e30f;
    }
    __syncthreads();

    // ---- S^T = K Q^T : s[t2][j] = S[key=kt+t2*16+lg*4+j][q=l15] ----
    f32x4 s[4];
    __builtin_amdgcn_s_setprio(1);
    #pragma unroll
    for (int t2 = 0; t2 < 4; t2++) {
      int key = t2 * 16 + l15;
      bf16x8 kb0 = ld_frag(&Ks[key * 64 + ((lg) ^ (key & 7)) * 8]);
      bf16x8 kb1 = ld_frag(&Ks[key * 64 + ((4 + lg) ^ (key & 7)) * 8]);
      f32x4 z = (f32x4){0.f, 0.f, 0.f, 0.f};
      z = __builtin_amdgcn_mfma_f32_16x16x32_bf16(kb0, qf0, z, 0, 0, 0);
      z = __builtin_amdgcn_mfma_f32_16x16x32_bf16(kb1, qf1, z, 0, 0, 0);
      s[t2] = z;
    }
    __builtin_amdgcn_s_setprio(0);

    // ---- p = exp2(s*SC + bias*log2e + mask); pack & write P[q=l15][key] ----
    #pragma unroll
    for (int t2 = 0; t2 < 4; t2++) {
      #pragma unroll
      for (int j = 0; j < 4; j++)
        s[t2][j] = exp2f(fmaf(s[t2][j], SC, bf_[t2][j]));
      uint2 pw;
      pw.x = cvtpk_bf16(s[t2][0], s[t2][1]);
      pw.y = cvtpk_bf16(s[t2][2], s[t2][3]);
      // keys t2*16+lg*4+j live in chunk c = 2*t2 + (lg>>1); physical c' = c ^ (q&7)
      const int cp = (2 * t2 + (lg >> 1)) ^ (l15 & 7);
      *(uint2*)&ptw[l15 * 64 + cp * 8 + (lg & 1) * 4] = pw;
    }

    // ---- PV: o[q,d] += P[q,key] V[key,d]; osum[q] += P[q,key] ----
    __builtin_amdgcn_s_setprio(1);
    #pragma unroll
    for (int ks = 0; ks < 2; ks++) {
      bf16x8 pa = ld_frag(&ptw[l15 * 64 + ((ks * 4 + lg) ^ (l15 & 7)) * 8]);
      osum = __builtin_amdgcn_mfma_f32_16x16x32_bf16(pa, ones, osum, 0, 0, 0);
      #pragma unroll
      for (int n = 0; n < 4; n++) {
        int d = n * 16 + l15;
        bf16x8 vb = ld_frag(&Vs[d * 64 + ((ks * 4 + lg) ^ (d & 7)) * 8]);
        o[n] = __builtin_amdgcn_mfma_f32_16x16x32_bf16(pa, vb, o[n], 0, 0, 0);
      }
    }
    __builtin_amdgcn_s_setprio(0);
  }

  // epilogue: normalize and store ctx (bf16, [B*T, D] with col = h*64+d)
  #pragma unroll
  for (int n = 0; n < 4; n++)
    #pragma unroll
    for (int j = 0; j < 4; j++) {
      int q = q0 + w * 16 + lg * 4 + j;
      ctx[(size_t)(b * Tc + q) * Dc + h * 64 + n * 16 + l15] = f2b(o[n][j] / osum[j]);
    }
}

// ---------------- launcher ----------------
extern "C" void kernel_launch(void* const* d_in, const int* in_sizes, int n_in,
                              void* d_out, int out_size, void* d_ws, size_t ws_size,
                              hipStream_t stream) {
  const float* x     = (const float*)d_in[0];
  const int*   amask = (const int*)d_in[1];
  const float* bias  = (const float*)d_in[2];
  const float* Wqkv  = (const float*)d_in[3];
  const float* Wout  = (const float*)d_in[4];
  float* out = (float*)d_out;
  char* ws = (char*)d_ws;

  // ws layout (bytes): xb 8,388,608 | wqkvT 1,572,864 | woutT 524,288 |
  //   qkv 25,165,824 | ctx 8,388,608 | vtg 8,388,608   (total ~52.4 MB)
  unsigned short* xb    = (unsigned short*)(ws + 0);
  unsigned short* wqkvT = (unsigned short*)(ws + 8388608);
  unsigned short* woutT = (unsigned short*)(ws + 9961472);
  unsigned short* qkv   = (unsigned short*)(ws + 10485760);
  unsigned short* ctx   = (unsigned short*)(ws + 35651584);
  unsigned short* vtg   = (unsigned short*)(ws + 44040192);

  cvt_bf16<<<2048, 256, 0, stream>>>(x, xb, Bc * Tc * Dc);
  transp_bf16<<<dim3(48, 16), 256, 0, stream>>>(Wqkv, wqkvT, 512, 1536);
  transp_bf16<<<dim3(16, 16), 256, 0, stream>>>(Wout, woutT, 512, 512);
  gemm_bt<1536, 0><<<dim3(64, 12), 256, 0, stream>>>(xb, wqkvT, (void*)qkv, 8192, 512);
  transp_v<<<dim3(64, 16, 4), 256, 0, stream>>>(qkv, vtg);
  attn_kernel<<<1024, 256, 0, stream>>>(qkv, vtg, bias, amask, ctx);
  gemm_bt<512, 1><<<dim3(64, 4), 256, 0, stream>>>(ctx, woutT, (void*)out, 8192, 512);
}